// Round 15
// baseline (1286.707 us; speedup 1.0000x reference)
//
#include <hip/hip_runtime.h>

typedef __bf16 bf16;
typedef bf16 bf16x8 __attribute__((ext_vector_type(8)));
typedef float f32x4 __attribute__((ext_vector_type(4)));
typedef unsigned int u32;

#define Vv 32000
#define Ee 512
#define Hh 1024
#define Bb 64
#define Ssz 64
#define Tt 32
#define TBm 2048
#define FFc 2048
#define G3c 3072
#define NBLKG 128

__device__ __forceinline__ float sigm(float x) { return 1.f / (1.f + expf(-x)); }

// device-coherent (bypass L1/L2; L3 is the coherence point)
__device__ __forceinline__ uint4 gload_sc(const void* p) {
  uint4 d;
  asm volatile("global_load_dwordx4 %0, %1, off sc0 sc1" : "=v"(d) : "v"(p));
  return d;
}
// plain asm loads (L2-cached) — asm so vmcnt counting stays exact
__device__ __forceinline__ uint4 gload16(const void* p) {
  uint4 d;
  asm volatile("global_load_dwordx4 %0, %1, off" : "=v"(d) : "v"(p));
  return d;
}
__device__ __forceinline__ u32 gload_p32(const void* p) {
  u32 d;
  asm volatile("global_load_dword %0, %1, off" : "=v"(d) : "v"(p));
  return d;
}
__device__ __forceinline__ void gstore_p32(void* p, u32 v) {
  asm volatile("global_store_dword %0, %1, off" :: "v"(p), "v"(v) : "memory");
}
__device__ __forceinline__ void gstore_sc16(void* p, u32 v) {
  asm volatile("global_store_short %0, %1, off sc0 sc1" :: "v"(p), "v"(v) : "memory");
}

__global__ void zero_k(u32* __restrict__ p, int n) {
  int i = blockIdx.x * blockDim.x + threadIdx.x;
  if (i < n) p[i] = 0u;
}

__global__ void cvt_simple_k(const float* __restrict__ s, bf16* __restrict__ d, int n) {
  int stride = gridDim.x * blockDim.x;
  for (int i = blockIdx.x * blockDim.x + threadIdx.x; i < n; i += stride)
    d[i] = (bf16)s[i];
}

__global__ void cvt_split_k(const float* __restrict__ s, bf16* __restrict__ hi,
                            bf16* __restrict__ lo, int n) {
  int stride = gridDim.x * blockDim.x;
  for (int i = blockIdx.x * blockDim.x + threadIdx.x; i < n; i += stride) {
    float v = s[i];
    bf16 h = (bf16)v;
    hi[i] = h;
    lo[i] = (bf16)(v - (float)h);
  }
}

// src[R][C] f32 -> dst[C][R] bf16
__global__ void transpose_cvt_k(const float* __restrict__ src, bf16* __restrict__ dst,
                                int R, int C) {
  __shared__ float tile[32][33];
  int bx = blockIdx.x * 32;  // C offset
  int by = blockIdx.y * 32;  // R offset
  int tx = threadIdx.x & 31, ty = threadIdx.x >> 5;
#pragma unroll
  for (int i = 0; i < 4; ++i) {
    int r = ty + i * 8;
    tile[r][tx] = src[(size_t)(by + r) * C + bx + tx];
  }
  __syncthreads();
#pragma unroll
  for (int i = 0; i < 4; ++i) {
    int r = ty + i * 8;
    dst[(size_t)(bx + r) * R + by + tx] = (bf16)tile[tx][r];
  }
}

__global__ void embed_k(const float* __restrict__ emb, const int* __restrict__ label,
                        bf16* __restrict__ xe) {
  int m = blockIdx.x;          // m = t*64 + b
  int t = m >> 6, b = m & 63;
  int tok = (t == 0) ? 1 : label[b * Tt + t - 1];
  const float* src = emb + (size_t)tok * Ee;
  bf16* dst = xe + (size_t)m * Ee;
  for (int e = threadIdx.x; e < Ee; e += blockDim.x) dst[e] = (bf16)src[e];
}

// C[m,n] = sum_k A[m,k]*Bt[n,k] + bias[n]; NT layout, bf16 in.
// MODE 0: f32 write  MODE 1: f32 ELU  MODE 2: bf16 write into the output
// row's own f32 slot (softmax expands later in place).
template <int MODE>
__global__ void __launch_bounds__(256) gemm_nt_k(
    const bf16* __restrict__ A, const bf16* __restrict__ Bt,
    const float* __restrict__ bias, float* __restrict__ C,
    int M, int N, int K) {
  __shared__ bf16 As[128 * 32];
  __shared__ bf16 Bs[128 * 32];
  const int tid = threadIdx.x;
  const int wv = tid >> 6, ln = tid & 63;
  const int wr = wv >> 1, wc = wv & 1;
  const int l15 = ln & 15, l4 = ln >> 4;

  int NX = gridDim.x, NY = gridDim.y;
  int nwg = NX * NY;
  int lin = blockIdx.x + blockIdx.y * NX;
  int bx, by;
  if ((nwg & 7) == 0) {
    int per = nwg >> 3;
    int virt = (lin & 7) * per + (lin >> 3);
    by = virt % NY;
    bx = virt / NY;
  } else {
    bx = blockIdx.x;
    by = blockIdx.y;
  }
  const int m0 = by * 128, n0 = bx * 128;

  const f32x4 vzero = {0.f, 0.f, 0.f, 0.f};
  f32x4 acc[4][4];
#pragma unroll
  for (int i = 0; i < 4; ++i) {
#pragma unroll
    for (int j = 0; j < 4; ++j) acc[i][j] = vzero;
  }

  const int nk = K >> 5;
  for (int kt = 0; kt < nk; ++kt) {
    const int k0 = kt << 5;
    __syncthreads();
#pragma unroll
    for (int it = 0; it < 2; ++it) {
      int c = tid + it * 256;
      int row = c >> 2, kc = (c & 3) << 3;
      *(uint4*)&As[row * 32 + kc] = *(const uint4*)(A + (size_t)(m0 + row) * K + k0 + kc);
      *(uint4*)&Bs[row * 32 + kc] = *(const uint4*)(Bt + (size_t)(n0 + row) * K + k0 + kc);
    }
    __syncthreads();
    bf16x8 af[4], bfv[4];
#pragma unroll
    for (int mt = 0; mt < 4; ++mt)
      af[mt] = *(const bf16x8*)&As[(wr * 64 + mt * 16 + l15) * 32 + l4 * 8];
#pragma unroll
    for (int nt = 0; nt < 4; ++nt)
      bfv[nt] = *(const bf16x8*)&Bs[(wc * 64 + nt * 16 + l15) * 32 + l4 * 8];
#pragma unroll
    for (int mt = 0; mt < 4; ++mt) {
#pragma unroll
      for (int nt = 0; nt < 4; ++nt)
        acc[mt][nt] = __builtin_amdgcn_mfma_f32_16x16x32_bf16(af[mt], bfv[nt], acc[mt][nt], 0, 0, 0);
    }
  }

#pragma unroll
  for (int mt = 0; mt < 4; ++mt) {
#pragma unroll
    for (int nt = 0; nt < 4; ++nt) {
      int col = wc * 64 + nt * 16 + l15;
      int n = n0 + col;
      float bv = bias[n];
#pragma unroll
      for (int r = 0; r < 4; ++r) {
        int row = wr * 64 + mt * 16 + l4 * 4 + r;
        int m = m0 + row;
        float v = acc[mt][nt][r] + bv;
        if (MODE == 1) v = (v > 0.f) ? v : expm1f(v);
        if (MODE == 2) {
          size_t R = (size_t)(m & 63) * Tt + (size_t)(m >> 6);
          ((bf16*)C)[2 * R * (size_t)Vv + (size_t)n] = (bf16)v;
        } else {
          C[(size_t)m * N + n] = v;
        }
      }
    }
  }
}

// ---------------- persistent GRU v9: K-half split, full j coverage ----------
// 128 blocks x 512 thr (8 waves). j8 = bid*8 -> FULL 1024 j coverage (the
// v8 bug was j8=(bid&31)*8, covering only 256 cols). Wave wv: btile=wv&3
// owns b-rows [btile*16,+16); khalf=wv>>2 owns K half [khalf*512,+512).
// Per-thread h loads: 32 (vs 64) in 4 chunks (vs 8) -> half the latency
// exposures; 8 waves/CU doubles TLP. K-half LDS reduce = R4/R7-proven.
// Hi-weights in 48KB LDS, lo-weights from L2, 8-line atomic barrier (R10).

#define ISSUE_CH(B, c)                                              \
  _Pragma("unroll")                                                 \
  for (int q = 0; q < 4; ++q) {                                     \
    int kk = (c) * 4 + q;                                           \
    int ke = kbase + kk * 32 + l4 * 8;                              \
    B##h[q] = gload_sc(hhi + hrow + ke);                            \
    B##l[q] = gload_sc(hlo + hrow + ke);                            \
    B##w0[q] = gload16(w0p + kk * 32);                              \
    B##w1[q] = gload16(w1p + kk * 32);                              \
  }

#define COMP_CH(B, c)                                               \
  _Pragma("unroll")                                                 \
  for (int q = 0; q < 4; ++q) {                                     \
    int kk = (c) * 4 + q;                                           \
    int sb = kb2 + (((kk * 4 + l4) << 4) ^ xor0);                   \
    bf16x8 bhi0 = *(const bf16x8*)(ldsW + rowoff0 + sb);            \
    bf16x8 bhi1 = *(const bf16x8*)(ldsW + 32768 + rowoff1 + sb);    \
    bf16x8 ahi = __builtin_bit_cast(bf16x8, B##h[q]);               \
    bf16x8 alo = __builtin_bit_cast(bf16x8, B##l[q]);               \
    bf16x8 w0v = __builtin_bit_cast(bf16x8, B##w0[q]);              \
    bf16x8 w1v = __builtin_bit_cast(bf16x8, B##w1[q]);              \
    acc0 = __builtin_amdgcn_mfma_f32_16x16x32_bf16(ahi, bhi0, acc0, 0, 0, 0); \
    acx0 = __builtin_amdgcn_mfma_f32_16x16x32_bf16(ahi, w0v, acx0, 0, 0, 0);  \
    acx0 = __builtin_amdgcn_mfma_f32_16x16x32_bf16(alo, bhi0, acx0, 0, 0, 0); \
    acc1 = __builtin_amdgcn_mfma_f32_16x16x32_bf16(ahi, bhi1, acc1, 0, 0, 0); \
    acx1 = __builtin_amdgcn_mfma_f32_16x16x32_bf16(ahi, w1v, acx1, 0, 0, 0);  \
    acx1 = __builtin_amdgcn_mfma_f32_16x16x32_bf16(alo, bhi1, acx1, 0, 0, 0); \
  }

#define WAIT16 { asm volatile("s_waitcnt vmcnt(16)" ::: "memory"); __builtin_amdgcn_sched_barrier(0); }
#define WAIT0  { asm volatile("s_waitcnt vmcnt(0)" ::: "memory");  __builtin_amdgcn_sched_barrier(0); }

__global__ void __launch_bounds__(512, 1) gru_all_k(
    const bf16* __restrict__ hHi0, const bf16* __restrict__ hLo0,
    bf16* __restrict__ hHi1, bf16* __restrict__ hLo1,
    const bf16* __restrict__ whhHi, const bf16* __restrict__ whhLo,
    const float* __restrict__ gates, const float* __restrict__ bhh,
    const float* __restrict__ h0, float* __restrict__ hseq,
    u32* __restrict__ bar) {
  __shared__ __align__(16) char ldsW[49152 + 8192];  // weights + reduce scratch
  float* sred = (float*)(ldsW + 49152);
  const int tid = threadIdx.x;
  const int wv = tid >> 6, ln = tid & 63;
  const int l15 = ln & 15, l4 = ln >> 4;
  const int bid = blockIdx.x;
  const int j8 = bid * 8;          // FULL j coverage: 128 blocks x 8 = 1024
  const int btile = wv & 3;        // b-tile [btile*16, +16)
  const int khalf = wv >> 2;       // K half
  const int kbase = khalf * 512;
  const int kb2 = kbase * 2;       // byte offset into LDS weight rows

  // ---- stage hi-weight slice into LDS (once): 24 rows x 1024 bf16 ----
  for (int idx = tid; idx < 24 * 128; idx += 512) {
    int row = idx >> 7;          // 0..23
    int seg = idx & 127;         // 16B segment within row
    int grow = (row < 8) ? (j8 + row)
             : (row < 16) ? (Hh + j8 + row - 8)
                          : (2 * Hh + j8 + row - 16);
    int rr = (row < 16) ? row : (row - 16);
    int region = (row < 16) ? 0 : 32768;
    int dst = region + rr * 2048 + ((seg * 16) ^ ((rr & 7) << 4));
    *(uint4*)(ldsW + dst) = *(const uint4*)(whhHi + (size_t)grow * Hh + seg * 8);
  }
  __syncthreads();

  const int rowoff0 = l15 * 2048;
  const int rowoff1 = (l15 & 7) * 2048;
  const int xor0 = (l15 & 7) << 4;

  const int cA = l15;
  const int grow0 = (cA < 8) ? (j8 + cA) : (Hh + j8 + cA - 8);
  const int grow1 = 2 * Hh + j8 + (cA & 7);
  const bf16* w0p = whhLo + (size_t)grow0 * Hh + kbase + l4 * 8;
  const bf16* w1p = whhLo + (size_t)grow1 * Hh + kbase + l4 * 8;

  const size_t hrow = (size_t)(btile * 16 + l15) * Hh;  // A-frag row

  const int jj = j8 + (cA & 7);
  int gbr[4];
#pragma unroll
  for (int r = 0; r < 4; ++r) gbr[r] = btile * 16 + l4 * 4 + r;
  const float* gAddr[4];
#pragma unroll
  for (int r = 0; r < 4; ++r) gAddr[r] = gates + (size_t)gbr[r] * G3c + jj;
  const float bhr = bhh[jj], bhz = bhh[Hh + jj], bhn = bhh[2 * Hh + jj];
  float hp[4];
#pragma unroll
  for (int r = 0; r < 4; ++r) hp[r] = h0[(size_t)gbr[r] * Hh + jj];

  const bf16* HIc[2] = {hHi0, hHi1};
  const bf16* LOc[2] = {hLo0, hLo1};
  bf16* HIm[2] = {(bf16*)hHi0, hHi1};
  bf16* LOm[2] = {(bf16*)hLo0, hLo1};
  const f32x4 vzero = {0.f, 0.f, 0.f, 0.f};

  for (int t = 0; t < Tt; ++t) {
    const bf16* hhi = HIc[t & 1];
    const bf16* hlo = LOc[t & 1];
    f32x4 acc0 = vzero, acx0 = vzero, acc1 = vzero, acx1 = vzero;
    uint4 Ah[4], Al[4], Aw0[4], Aw1[4];
    uint4 Bh[4], Bl[4], Bw0[4], Bw1[4];
    uint4 Ch[4], Cl[4], Cw0[4], Cw1[4];

    // gates prefetch (12 dwords, ALL waves -> symmetric vmcnt; oldest in
    // queue, complete by the first WAIT16)
    u32 gR[4], gZ[4], gN[4];
    const size_t gt = (size_t)t * Bb * G3c;
#pragma unroll
    for (int r = 0; r < 4; ++r) {
      gR[r] = gload_p32(gAddr[r] + gt);
      gZ[r] = gload_p32(gAddr[r] + gt + Hh);
      gN[r] = gload_p32(gAddr[r] + gt + 2 * Hh);
    }

    ISSUE_CH(A, 0) ISSUE_CH(B, 1) WAIT16   // gates + chunk0 done
    COMP_CH(A, 0)  ISSUE_CH(C, 2) WAIT16   // chunk1 done
    COMP_CH(B, 1)  ISSUE_CH(A, 3) WAIT16   // chunk2 done
    COMP_CH(C, 2)  WAIT0                   // chunk3 done
    COMP_CH(A, 3)

    // ---- K-half reduce: khalf==1 waves -> LDS, khalf==0 accumulate ----
    f32x4 s0 = acc0 + acx0;
    f32x4 s1 = acc1 + acx1;
    if (khalf == 1) {
      *(f32x4*)&sred[(btile * 2 + 0) * 256 + ln * 4] = s0;
      *(f32x4*)&sred[(btile * 2 + 1) * 256 + ln * 4] = s1;
    }
    __syncthreads();
    if (khalf == 0) {
      s0 += *(const f32x4*)&sred[(btile * 2 + 0) * 256 + ln * 4];
      s1 += *(const f32x4*)&sred[(btile * 2 + 1) * 256 + ln * 4];
      float s0r[4], s1r[4], sZ[4];
#pragma unroll
      for (int r = 0; r < 4; ++r) { s0r[r] = s0[r]; s1r[r] = s1[r]; }
#pragma unroll
      for (int r = 0; r < 4; ++r) sZ[r] = __shfl_xor(s0r[r], 8);

      if (cA < 8) {
        float* hout = hseq + (size_t)t * Bb * Hh;
        bf16* nhi = HIm[(t + 1) & 1];
        bf16* nlo = LOm[(t + 1) & 1];
#pragma unroll
        for (int r = 0; r < 4; ++r) {
          float rg = sigm(__builtin_bit_cast(float, gR[r]) + s0r[r] + bhr);
          float zg = sigm(__builtin_bit_cast(float, gZ[r]) + sZ[r] + bhz);
          float ng = tanhf(__builtin_bit_cast(float, gN[r]) + rg * (s1r[r] + bhn));
          float hv = (1.f - zg) * ng + zg * hp[r];
          hp[r] = hv;
          size_t o = (size_t)gbr[r] * Hh + jj;
          gstore_p32(hout + o, __builtin_bit_cast(u32, hv));
          bf16 hb = (bf16)hv;
          bf16 lb = (bf16)(hv - (float)hb);
          gstore_sc16(nhi + o, (u32)__builtin_bit_cast(unsigned short, hb));
          gstore_sc16(nlo + o, (u32)__builtin_bit_cast(unsigned short, lb));
        }
      }
    }

    if (t < Tt - 1) {
      __syncthreads();  // per-wave vmcnt(0) drain: h stores visible at L3
      if (tid == 0) {
        __hip_atomic_fetch_add(bar + (bid & 7) * 32, 1u,
                               __ATOMIC_RELAXED, __HIP_MEMORY_SCOPE_AGENT);
      }
      if (wv == 0) {
        unsigned target = (unsigned)(t + 1) * (NBLKG / 8);  // 16 per line
        bool ok;
        do {
          unsigned v = 0xFFFFFFFFu;
          if (ln < 8)
            v = __hip_atomic_load(bar + ln * 32, __ATOMIC_RELAXED,
                                  __HIP_MEMORY_SCOPE_AGENT);
          ok = __all((ln >= 8) || (v >= target));
          if (!ok) __builtin_amdgcn_s_sleep(1);
        } while (!ok);
      }
      __syncthreads();
    }
  }
}

// dot attention + feat=concat(h,ctx). One block per (t,b).
__global__ void __launch_bounds__(256) attn_k(
    const float* __restrict__ hseq, const float* __restrict__ enc,
    float* __restrict__ feat) {
  __shared__ float red[256];
  __shared__ float wsm[Ssz];
  int m = blockIdx.x;
  int t = m >> 6, b = m & 63;
  const float* hv = hseq + (size_t)t * Bb * Hh + (size_t)b * Hh;
  const float* eb = enc + (size_t)b * Ssz * Hh;
  int tid = threadIdx.x;
  int s = tid >> 2, q = tid & 3;
  const float* er = eb + (size_t)s * Hh + q * 256;
  const float* hq = hv + q * 256;
  float p = 0.f;
#pragma unroll 4
  for (int i = 0; i < 256; i += 4) {
    float4 a = *(const float4*)(hq + i);
    float4 c = *(const float4*)(er + i);
    p += a.x * c.x + a.y * c.y + a.z * c.z + a.w * c.w;
  }
  red[tid] = p;
  __syncthreads();
  if (tid < 64) {
    float sc = red[tid * 4] + red[tid * 4 + 1] + red[tid * 4 + 2] + red[tid * 4 + 3];
    float mx = sc;
#pragma unroll
    for (int off = 32; off > 0; off >>= 1) mx = fmaxf(mx, __shfl_xor(mx, off));
    float e = expf(sc - mx);
    float sm = e;
#pragma unroll
    for (int off = 32; off > 0; off >>= 1) sm += __shfl_xor(sm, off);
    wsm[tid] = e / sm;
  }
  __syncthreads();
  float* fr = feat + (size_t)m * FFc;
  for (int h = tid; h < Hh; h += 256) {
    float a = 0.f;
#pragma unroll 8
    for (int si = 0; si < Ssz; ++si) a = fmaf(wsm[si], eb[(size_t)si * Hh + h], a);
    fr[Hh + h] = a;
    fr[h] = hv[h];
  }
}

// training-mode BN over batch dim (per t). grid (CH/256, T)
__global__ void __launch_bounds__(256) bn_k(
    const float* __restrict__ x, const float* __restrict__ gam,
    const float* __restrict__ bet, bf16* __restrict__ y, int CH) {
  int t = blockIdx.y;
  int c = blockIdx.x * 256 + threadIdx.x;
  const float* xp = x + (size_t)t * Bb * CH + c;
  float v[Bb];
  float s = 0.f, ss = 0.f;
#pragma unroll
  for (int b = 0; b < Bb; ++b) {
    float u = xp[(size_t)b * CH];
    v[b] = u;
    s += u;
    ss += u * u;
  }
  float mean = s * (1.f / Bb);
  float var = ss * (1.f / Bb) - mean * mean;
  float inv = rsqrtf(var + 1e-5f);
  float sc = gam[c] * inv;
  float sh = bet[c] - mean * sc;
  bf16* yp = y + (size_t)t * Bb * CH + c;
#pragma unroll
  for (int b = 0; b < Bb; ++b) yp[(size_t)b * CH] = (bf16)(v[b] * sc + sh);
}

// softmax over V: bf16 logits (in the row's own f32 slot) -> f32 probs.
// Row held in registers (16 uint4/thread): one global read, one write.
__global__ void __launch_bounds__(256) softmax_k(float* __restrict__ out) {
  __shared__ float rm[256], rs[256];
  int m = blockIdx.x;
  int t = m >> 6, b = m & 63;
  size_t R = (size_t)b * Tt + t;
  const bf16* rin = (const bf16*)out + 2 * R * (size_t)Vv;
  float* rout = out + R * (size_t)Vv;
  int tid = threadIdx.x;
  uint4 v[16];
  float mx = -3.0e38f, sm = 0.f;
#pragma unroll
  for (int j = 0; j < 16; ++j) {
    int i = tid * 8 + j * 2048;
    if (i < Vv) {
      v[j] = *(const uint4*)(rin + i);
      const bf16* pv = (const bf16*)&v[j];
      float f0 = (float)pv[0], f1 = (float)pv[1], f2 = (float)pv[2], f3 = (float)pv[3];
      float f4 = (float)pv[4], f5 = (float)pv[5], f6 = (float)pv[6], f7 = (float)pv[7];
      float m8 = fmaxf(fmaxf(fmaxf(f0, f1), fmaxf(f2, f3)),
                       fmaxf(fmaxf(f4, f5), fmaxf(f6, f7)));
      if (m8 > mx) { sm *= expf(mx - m8); mx = m8; }
      sm += expf(f0 - mx) + expf(f1 - mx) + expf(f2 - mx) + expf(f3 - mx)
          + expf(f4 - mx) + expf(f5 - mx) + expf(f6 - mx) + expf(f7 - mx);
    }
  }
  rm[tid] = mx;
  rs[tid] = sm;
  __syncthreads();
  for (int off = 128; off > 0; off >>= 1) {
    if (tid < off) {
      float ma = rm[tid], mb = rm[tid + off];
      float m2 = fmaxf(ma, mb);
      rs[tid] = rs[tid] * expf(ma - m2) + rs[tid + off] * expf(mb - m2);
      rm[tid] = m2;
    }
    __syncthreads();
  }
  float M = rm[0];
  float inv = 1.f / rs[0];
#pragma unroll
  for (int j = 0; j < 16; ++j) {
    int i = tid * 8 + j * 2048;
    if (i < Vv) {
      const bf16* pv = (const bf16*)&v[j];
      float4 o0, o1;
      o0.x = expf((float)pv[0] - M) * inv;
      o0.y = expf((float)pv[1] - M) * inv;
      o0.z = expf((float)pv[2] - M) * inv;
      o0.w = expf((float)pv[3] - M) * inv;
      o1.x = expf((float)pv[4] - M) * inv;
      o1.y = expf((float)pv[5] - M) * inv;
      o1.z = expf((float)pv[6] - M) * inv;
      o1.w = expf((float)pv[7] - M) * inv;
      *(float4*)(rout + i) = o0;
      *(float4*)(rout + i + 4) = o1;
    }
  }
}

__global__ void hlast_k(const float* __restrict__ src, float* __restrict__ dst) {
  int i = blockIdx.x * 256 + threadIdx.x;
  dst[i] = src[i];
}

extern "C" void kernel_launch(void* const* d_in, const int* in_sizes, int n_in,
                              void* d_out, int out_size, void* d_ws, size_t ws_size,
                              hipStream_t stream) {
  const float* enc   = (const float*)d_in[0];
  const int*   label = (const int*)d_in[1];
  const float* h0    = (const float*)d_in[2];
  // d_in[3] answer_lens: unused by the forward pass
  const float* emb   = (const float*)d_in[4];
  const float* w_ih  = (const float*)d_in[5];
  const float* w_hh  = (const float*)d_in[6];
  const float* b_ih  = (const float*)d_in[7];
  const float* b_hh  = (const float*)d_in[8];
  const float* bn1g  = (const float*)d_in[9];
  const float* bn1b  = (const float*)d_in[10];
  const float* W1    = (const float*)d_in[11];
  const float* b1    = (const float*)d_in[12];
  const float* bn2g  = (const float*)d_in[13];
  const float* bn2b  = (const float*)d_in[14];
  const float* W2    = (const float*)d_in[15];
  const float* b2    = (const float*)d_in[16];
  float* out = (float*)d_out;
  (void)in_sizes; (void)n_in; (void)out_size; (void)ws_size;

  char* ws = (char*)d_ws;
  size_t off = 0;
  auto alloc = [&](size_t bytes) -> void* {
    void* p = ws + off;
    off += (bytes + 255) & ~(size_t)255;
    return p;
  };
  // workspace layout IDENTICAL to round-13 green run
  bf16*  W2t   = (bf16*)alloc((size_t)Vv * Hh * 2);        // 64 MB
  bf16*  W1t   = (bf16*)alloc((size_t)Hh * FFc * 2);       // 4 MB
  bf16*  wihB  = (bf16*)alloc((size_t)G3c * Ee * 2);       // 3 MB
  bf16*  whhHi = (bf16*)alloc((size_t)G3c * Hh * 2);       // 6 MB
  bf16*  whhLo = (bf16*)alloc((size_t)G3c * Hh * 2);       // 6 MB
  bf16*  xeB   = (bf16*)alloc((size_t)TBm * Ee * 2);       // 2 MB
  float* gates = (float*)alloc((size_t)TBm * G3c * 4);     // 25 MB
  float* hseq  = (float*)alloc((size_t)Tt * Bb * Hh * 4);  // 8 MB
  bf16*  hHi0  = (bf16*)alloc((size_t)Bb * Hh * 2);
  bf16*  hHi1  = (bf16*)alloc((size_t)Bb * Hh * 2);
  bf16*  hLo0  = (bf16*)alloc((size_t)Bb * Hh * 2);
  bf16*  hLo1  = (bf16*)alloc((size_t)Bb * Hh * 2);
  u32*   bar   = (u32*)alloc(2048);                        // 8 counter lines
  float* feat  = gates;  // alias: gates dead after GRU; 16 MB <= 25 MB
  bf16*  featB = (bf16*)alloc((size_t)TBm * FFc * 2);      // 8 MB
  float* Y     = (float*)alloc((size_t)TBm * Hh * 4);      // 8 MB
  bf16*  ybB   = (bf16*)alloc((size_t)TBm * Hh * 2);       // 4 MB

  // ---- zero barrier counters (re-zeroed every launch; graph-safe) ----
  zero_k<<<1, 512, 0, stream>>>(bar, 512);

  // ---- weight prep ----
  cvt_simple_k<<<1024, 256, 0, stream>>>(w_ih, wihB, G3c * Ee);
  cvt_split_k<<<2048, 256, 0, stream>>>(w_hh, whhHi, whhLo, G3c * Hh);
  transpose_cvt_k<<<dim3(Hh / 32, FFc / 32), 256, 0, stream>>>(W1, W1t, FFc, Hh);
  transpose_cvt_k<<<dim3(Vv / 32, Hh / 32), 256, 0, stream>>>(W2, W2t, Hh, Vv);
  embed_k<<<TBm, 128, 0, stream>>>(emb, label, xeB);
  cvt_split_k<<<256, 256, 0, stream>>>(h0, hHi0, hLo0, Bb * Hh);

  // ---- gates_x = x_emb @ w_ih^T + b_ih  [TB, 3H] ----
  gemm_nt_k<0><<<dim3(G3c / 128, TBm / 128), 256, 0, stream>>>(
      xeB, wihB, b_ih, gates, TBm, G3c, Ee);

  // ---- fused sequential GRU (persistent, K-half split, full j coverage) ----
  gru_all_k<<<NBLKG, 512, 0, stream>>>(
      hHi0, hLo0, hHi1, hLo1, whhHi, whhLo, gates, b_hh, h0, hseq, bar);

  // ---- batched post-recurrence pipeline ----
  attn_k<<<TBm, 256, 0, stream>>>(hseq, enc, feat);
  bn_k<<<dim3(FFc / 256, Tt), 256, 0, stream>>>(feat, bn1g, bn1b, featB, FFc);
  gemm_nt_k<1><<<dim3(Hh / 128, TBm / 128), 256, 0, stream>>>(
      featB, W1t, b1, Y, TBm, Hh, FFc);
  bn_k<<<dim3(Hh / 256, Tt), 256, 0, stream>>>(Y, bn2g, bn2b, ybB, Hh);
  gemm_nt_k<2><<<dim3(Vv / 128, TBm / 128), 256, 0, stream>>>(
      ybB, W2t, b2, out, TBm, Vv, Hh);
  softmax_k<<<TBm, 256, 0, stream>>>(out);
  hlast_k<<<(Bb * Hh) / 256, 256, 0, stream>>>(
      hseq + (size_t)(Tt - 1) * Bb * Hh, out + (size_t)Bb * Tt * Vv);
}

// Round 16
// 1132.061 us; speedup vs baseline: 1.1366x; 1.1366x over previous
//
#include <hip/hip_runtime.h>

typedef __bf16 bf16;
typedef bf16 bf16x8 __attribute__((ext_vector_type(8)));
typedef float f32x4 __attribute__((ext_vector_type(4)));
typedef unsigned int u32;

#define Vv 32000
#define Ee 512
#define Hh 1024
#define Bb 64
#define Ssz 64
#define Tt 32
#define TBm 2048
#define FFc 2048
#define G3c 3072
#define NBLKG 128

__device__ __forceinline__ float sigm(float x) { return 1.f / (1.f + expf(-x)); }

// device-coherent (bypass L1/L2; L3 is the coherence point)
__device__ __forceinline__ uint4 gload_sc(const void* p) {
  uint4 d;
  asm volatile("global_load_dwordx4 %0, %1, off sc0 sc1" : "=v"(d) : "v"(p));
  return d;
}
// plain asm loads (L2-cached) — asm so vmcnt counting stays exact
__device__ __forceinline__ uint4 gload16(const void* p) {
  uint4 d;
  asm volatile("global_load_dwordx4 %0, %1, off" : "=v"(d) : "v"(p));
  return d;
}
__device__ __forceinline__ u32 gload_p32(const void* p) {
  u32 d;
  asm volatile("global_load_dword %0, %1, off" : "=v"(d) : "v"(p));
  return d;
}
__device__ __forceinline__ void gstore_p32(void* p, u32 v) {
  asm volatile("global_store_dword %0, %1, off" :: "v"(p), "v"(v) : "memory");
}
__device__ __forceinline__ void gstore_sc16(void* p, u32 v) {
  asm volatile("global_store_short %0, %1, off sc0 sc1" :: "v"(p), "v"(v) : "memory");
}

__global__ void zero_k(u32* __restrict__ p, int n) {
  int i = blockIdx.x * blockDim.x + threadIdx.x;
  if (i < n) p[i] = 0u;
}

__global__ void cvt_simple_k(const float* __restrict__ s, bf16* __restrict__ d, int n) {
  int stride = gridDim.x * blockDim.x;
  for (int i = blockIdx.x * blockDim.x + threadIdx.x; i < n; i += stride)
    d[i] = (bf16)s[i];
}

__global__ void cvt_split_k(const float* __restrict__ s, bf16* __restrict__ hi,
                            bf16* __restrict__ lo, int n) {
  int stride = gridDim.x * blockDim.x;
  for (int i = blockIdx.x * blockDim.x + threadIdx.x; i < n; i += stride) {
    float v = s[i];
    bf16 h = (bf16)v;
    hi[i] = h;
    lo[i] = (bf16)(v - (float)h);
  }
}

// src[R][C] f32 -> dst[C][R] bf16
__global__ void transpose_cvt_k(const float* __restrict__ src, bf16* __restrict__ dst,
                                int R, int C) {
  __shared__ float tile[32][33];
  int bx = blockIdx.x * 32;  // C offset
  int by = blockIdx.y * 32;  // R offset
  int tx = threadIdx.x & 31, ty = threadIdx.x >> 5;
#pragma unroll
  for (int i = 0; i < 4; ++i) {
    int r = ty + i * 8;
    tile[r][tx] = src[(size_t)(by + r) * C + bx + tx];
  }
  __syncthreads();
#pragma unroll
  for (int i = 0; i < 4; ++i) {
    int r = ty + i * 8;
    dst[(size_t)(bx + r) * R + by + tx] = (bf16)tile[tx][r];
  }
}

__global__ void embed_k(const float* __restrict__ emb, const int* __restrict__ label,
                        bf16* __restrict__ xe) {
  int m = blockIdx.x;          // m = t*64 + b
  int t = m >> 6, b = m & 63;
  int tok = (t == 0) ? 1 : label[b * Tt + t - 1];
  const float* src = emb + (size_t)tok * Ee;
  bf16* dst = xe + (size_t)m * Ee;
  for (int e = threadIdx.x; e < Ee; e += blockDim.x) dst[e] = (bf16)src[e];
}

// C[m,n] = sum_k A[m,k]*Bt[n,k] + bias[n]; NT layout, bf16 in.
// BK=64 (half the barrier drains of BK=32) with XOR-swizzled LDS
// (byte ^= (row&7)<<4 on store AND read: stride-128B rows would otherwise
// be a 16-way bank conflict; swizzled reads are 2-way = free).
// MODE 0: f32 write  MODE 1: f32 ELU  MODE 2: bf16 write into the output
// row's own f32 slot (softmax expands later in place).
template <int MODE>
__global__ void __launch_bounds__(256) gemm_nt_k(
    const bf16* __restrict__ A, const bf16* __restrict__ Bt,
    const float* __restrict__ bias, float* __restrict__ C,
    int M, int N, int K) {
  __shared__ __align__(16) char As[128 * 128];  // 128 rows x 64 bf16
  __shared__ __align__(16) char Bs[128 * 128];
  const int tid = threadIdx.x;
  const int wv = tid >> 6, ln = tid & 63;
  const int wr = wv >> 1, wc = wv & 1;
  const int l15 = ln & 15, l4 = ln >> 4;

  int NX = gridDim.x, NY = gridDim.y;
  int nwg = NX * NY;
  int lin = blockIdx.x + blockIdx.y * NX;
  int bx, by;
  if ((nwg & 7) == 0) {
    int per = nwg >> 3;
    int virt = (lin & 7) * per + (lin >> 3);
    by = virt % NY;
    bx = virt / NY;
  } else {
    bx = blockIdx.x;
    by = blockIdx.y;
  }
  const int m0 = by * 128, n0 = bx * 128;

  const f32x4 vzero = {0.f, 0.f, 0.f, 0.f};
  f32x4 acc[4][4];
#pragma unroll
  for (int i = 0; i < 4; ++i) {
#pragma unroll
    for (int j = 0; j < 4; ++j) acc[i][j] = vzero;
  }

  const int nk = K >> 6;
  for (int kt = 0; kt < nk; ++kt) {
    const int k0 = kt << 6;
    __syncthreads();
#pragma unroll
    for (int it = 0; it < 4; ++it) {
      int s = tid + it * 256;            // 0..1023 16B segments
      int row = s >> 3, c8 = s & 7;
      int dst = row * 128 + ((c8 * 16) ^ ((row & 7) << 4));
      *(uint4*)(As + dst) = *(const uint4*)(A + (size_t)(m0 + row) * K + k0 + c8 * 8);
      *(uint4*)(Bs + dst) = *(const uint4*)(Bt + (size_t)(n0 + row) * K + k0 + c8 * 8);
    }
    __syncthreads();
#pragma unroll
    for (int kk = 0; kk < 2; ++kk) {
      bf16x8 af[4], bfv[4];
#pragma unroll
      for (int mt = 0; mt < 4; ++mt) {
        int row = wr * 64 + mt * 16 + l15;
        int boff = row * 128 + (((kk * 64) + l4 * 16) ^ ((row & 7) << 4));
        af[mt] = *(const bf16x8*)(As + boff);
      }
#pragma unroll
      for (int nt = 0; nt < 4; ++nt) {
        int row = wc * 64 + nt * 16 + l15;
        int boff = row * 128 + (((kk * 64) + l4 * 16) ^ ((row & 7) << 4));
        bfv[nt] = *(const bf16x8*)(Bs + boff);
      }
#pragma unroll
      for (int mt = 0; mt < 4; ++mt) {
#pragma unroll
        for (int nt = 0; nt < 4; ++nt)
          acc[mt][nt] = __builtin_amdgcn_mfma_f32_16x16x32_bf16(af[mt], bfv[nt], acc[mt][nt], 0, 0, 0);
      }
    }
  }

#pragma unroll
  for (int mt = 0; mt < 4; ++mt) {
#pragma unroll
    for (int nt = 0; nt < 4; ++nt) {
      int col = wc * 64 + nt * 16 + l15;
      int n = n0 + col;
      float bv = bias[n];
#pragma unroll
      for (int r = 0; r < 4; ++r) {
        int row = wr * 64 + mt * 16 + l4 * 4 + r;
        int m = m0 + row;
        float v = acc[mt][nt][r] + bv;
        if (MODE == 1) v = (v > 0.f) ? v : expm1f(v);
        if (MODE == 2) {
          size_t R = (size_t)(m & 63) * Tt + (size_t)(m >> 6);
          ((bf16*)C)[2 * R * (size_t)Vv + (size_t)n] = (bf16)v;
        } else {
          C[(size_t)m * N + n] = v;
        }
      }
    }
  }
}

// ---------------- persistent GRU (R13-exact, proven 592us) ----------------
// 128 blocks x 256 thr, hi-weights in 48KB static LDS, lo-weights streamed
// from L2, h via coherent loads, counted vmcnt pipeline, 8-line atomic
// barrier.

#define ISSUE_CH(B, c)                                              \
  _Pragma("unroll")                                                 \
  for (int q = 0; q < 4; ++q) {                                     \
    int kk = (c) * 4 + q;                                           \
    int ke = kk * 32 + l4 * 8;                                      \
    B##h[q] = gload_sc(hhi + hrow + ke);                            \
    B##l[q] = gload_sc(hlo + hrow + ke);                            \
    B##w0[q] = gload16(w0p + kk * 32);                              \
    B##w1[q] = gload16(w1p + kk * 32);                              \
  }

#define COMP_CH(B, c)                                               \
  _Pragma("unroll")                                                 \
  for (int q = 0; q < 4; ++q) {                                     \
    int kk = (c) * 4 + q;                                           \
    int sb = (kk * 4 + l4) << 4;                                    \
    bf16x8 bhi0 = *(const bf16x8*)(ldsW + rowoff0 + (sb ^ xor0));   \
    bf16x8 bhi1 = *(const bf16x8*)(ldsW + 32768 + rowoff1 + (sb ^ xor0)); \
    bf16x8 ahi = __builtin_bit_cast(bf16x8, B##h[q]);               \
    bf16x8 alo = __builtin_bit_cast(bf16x8, B##l[q]);               \
    bf16x8 w0v = __builtin_bit_cast(bf16x8, B##w0[q]);              \
    bf16x8 w1v = __builtin_bit_cast(bf16x8, B##w1[q]);              \
    acc0 = __builtin_amdgcn_mfma_f32_16x16x32_bf16(ahi, bhi0, acc0, 0, 0, 0); \
    acx0 = __builtin_amdgcn_mfma_f32_16x16x32_bf16(ahi, w0v, acx0, 0, 0, 0);  \
    acx0 = __builtin_amdgcn_mfma_f32_16x16x32_bf16(alo, bhi0, acx0, 0, 0, 0); \
    acc1 = __builtin_amdgcn_mfma_f32_16x16x32_bf16(ahi, bhi1, acc1, 0, 0, 0); \
    acx1 = __builtin_amdgcn_mfma_f32_16x16x32_bf16(ahi, w1v, acx1, 0, 0, 0);  \
    acx1 = __builtin_amdgcn_mfma_f32_16x16x32_bf16(alo, bhi1, acx1, 0, 0, 0); \
  }

#define WAIT16 { asm volatile("s_waitcnt vmcnt(16)" ::: "memory"); __builtin_amdgcn_sched_barrier(0); }
#define WAIT0  { asm volatile("s_waitcnt vmcnt(0)" ::: "memory");  __builtin_amdgcn_sched_barrier(0); }

__global__ void __launch_bounds__(256, 1) gru_all_k(
    const bf16* __restrict__ hHi0, const bf16* __restrict__ hLo0,
    bf16* __restrict__ hHi1, bf16* __restrict__ hLo1,
    const bf16* __restrict__ whhHi, const bf16* __restrict__ whhLo,
    const float* __restrict__ gates, const float* __restrict__ bhh,
    const float* __restrict__ h0, float* __restrict__ hseq,
    u32* __restrict__ bar) {
  __shared__ __align__(16) char ldsW[49152];
  const int tid = threadIdx.x;
  const int wv = tid >> 6, ln = tid & 63;
  const int l15 = ln & 15, l4 = ln >> 4;
  const int bid = blockIdx.x;
  const int j8 = bid * 8;

  // ---- stage hi-weight slice into LDS (once): 24 rows x 1024 bf16 ----
  for (int idx = tid; idx < 24 * 128; idx += 256) {
    int row = idx >> 7;          // 0..23
    int seg = idx & 127;         // 16B segment within row
    int grow = (row < 8) ? (j8 + row)
             : (row < 16) ? (Hh + j8 + row - 8)
                          : (2 * Hh + j8 + row - 16);
    int rr = (row < 16) ? row : (row - 16);
    int region = (row < 16) ? 0 : 32768;
    int dst = region + rr * 2048 + ((seg * 16) ^ ((rr & 7) << 4));
    *(uint4*)(ldsW + dst) = *(const uint4*)(whhHi + (size_t)grow * Hh + seg * 8);
  }
  __syncthreads();

  const int rowoff0 = l15 * 2048;
  const int rowoff1 = (l15 & 7) * 2048;
  const int xor0 = (l15 & 7) << 4;

  const int cA = l15;
  const int grow0 = (cA < 8) ? (j8 + cA) : (Hh + j8 + cA - 8);
  const int grow1 = 2 * Hh + j8 + (cA & 7);
  const bf16* w0p = whhLo + (size_t)grow0 * Hh + l4 * 8;
  const bf16* w1p = whhLo + (size_t)grow1 * Hh + l4 * 8;

  const size_t hrow = (size_t)(wv * 16 + l15) * Hh;

  const int jj = j8 + (cA & 7);
  int gbr[4];
#pragma unroll
  for (int r = 0; r < 4; ++r) gbr[r] = wv * 16 + (ln >> 4) * 4 + r;
  const float* gAddr[4];
#pragma unroll
  for (int r = 0; r < 4; ++r) gAddr[r] = gates + (size_t)gbr[r] * G3c + jj;
  const float bhr = bhh[jj], bhz = bhh[Hh + jj], bhn = bhh[2 * Hh + jj];
  float hp[4];
#pragma unroll
  for (int r = 0; r < 4; ++r) hp[r] = h0[(size_t)gbr[r] * Hh + jj];

  const bf16* HIc[2] = {hHi0, hHi1};
  const bf16* LOc[2] = {hLo0, hLo1};
  bf16* HIm[2] = {(bf16*)hHi0, hHi1};
  bf16* LOm[2] = {(bf16*)hLo0, hLo1};
  const f32x4 vzero = {0.f, 0.f, 0.f, 0.f};

  for (int t = 0; t < Tt; ++t) {
    const bf16* hhi = HIc[t & 1];
    const bf16* hlo = LOc[t & 1];
    f32x4 acc0 = vzero, acx0 = vzero, acc1 = vzero, acx1 = vzero;
    uint4 Ah[4], Al[4], Aw0[4], Aw1[4];
    uint4 Bh[4], Bl[4], Bw0[4], Bw1[4];
    uint4 Ch[4], Cl[4], Cw0[4], Cw1[4];

    // gates prefetch (12 dwords; oldest in queue, done by first WAIT16)
    u32 gR[4], gZ[4], gN[4];
    const size_t gt = (size_t)t * Bb * G3c;
#pragma unroll
    for (int r = 0; r < 4; ++r) {
      gR[r] = gload_p32(gAddr[r] + gt);
      gZ[r] = gload_p32(gAddr[r] + gt + Hh);
      gN[r] = gload_p32(gAddr[r] + gt + 2 * Hh);
    }

    ISSUE_CH(A, 0) ISSUE_CH(B, 1) WAIT16
    COMP_CH(A, 0)  ISSUE_CH(C, 2) WAIT16
    COMP_CH(B, 1)  ISSUE_CH(A, 3) WAIT16
    COMP_CH(C, 2)  ISSUE_CH(B, 4) WAIT16
    COMP_CH(A, 3)  ISSUE_CH(C, 5) WAIT16
    COMP_CH(B, 4)  ISSUE_CH(A, 6) WAIT16
    COMP_CH(C, 5)  ISSUE_CH(B, 7) WAIT16
    COMP_CH(A, 6)  WAIT0
    COMP_CH(B, 7)

    // ---- epilogue ----
    float s0r[4], s1r[4], sZ[4];
#pragma unroll
    for (int r = 0; r < 4; ++r) {
      s0r[r] = acc0[r] + acx0[r];
      s1r[r] = acc1[r] + acx1[r];
    }
#pragma unroll
    for (int r = 0; r < 4; ++r) sZ[r] = __shfl_xor(s0r[r], 8);

    if (cA < 8) {
      float* hout = hseq + (size_t)t * Bb * Hh;
      bf16* nhi = HIm[(t + 1) & 1];
      bf16* nlo = LOm[(t + 1) & 1];
#pragma unroll
      for (int r = 0; r < 4; ++r) {
        float rg = sigm(__builtin_bit_cast(float, gR[r]) + s0r[r] + bhr);
        float zg = sigm(__builtin_bit_cast(float, gZ[r]) + sZ[r] + bhz);
        float ng = tanhf(__builtin_bit_cast(float, gN[r]) + rg * (s1r[r] + bhn));
        float hv = (1.f - zg) * ng + zg * hp[r];
        hp[r] = hv;
        size_t o = (size_t)gbr[r] * Hh + jj;
        gstore_p32(hout + o, __builtin_bit_cast(u32, hv));
        bf16 hb = (bf16)hv;
        bf16 lb = (bf16)(hv - (float)hb);
        gstore_sc16(nhi + o, (u32)__builtin_bit_cast(unsigned short, hb));
        gstore_sc16(nlo + o, (u32)__builtin_bit_cast(unsigned short, lb));
      }
    }

    if (t < Tt - 1) {
      __syncthreads();  // per-wave vmcnt(0) drain: h stores visible at L3
      if (tid == 0) {
        __hip_atomic_fetch_add(bar + (bid & 7) * 32, 1u,
                               __ATOMIC_RELAXED, __HIP_MEMORY_SCOPE_AGENT);
      }
      if (wv == 0) {
        unsigned target = (unsigned)(t + 1) * (NBLKG / 8);  // 16 per line
        bool ok;
        do {
          unsigned v = 0xFFFFFFFFu;
          if (ln < 8)
            v = __hip_atomic_load(bar + ln * 32, __ATOMIC_RELAXED,
                                  __HIP_MEMORY_SCOPE_AGENT);
          ok = __all((ln >= 8) || (v >= target));
          if (!ok) __builtin_amdgcn_s_sleep(1);
        } while (!ok);
      }
      __syncthreads();
    }
  }
}

// dot attention + feat=concat(h,ctx). One block per (t,b).
__global__ void __launch_bounds__(256) attn_k(
    const float* __restrict__ hseq, const float* __restrict__ enc,
    float* __restrict__ feat) {
  __shared__ float red[256];
  __shared__ float wsm[Ssz];
  int m = blockIdx.x;
  int t = m >> 6, b = m & 63;
  const float* hv = hseq + (size_t)t * Bb * Hh + (size_t)b * Hh;
  const float* eb = enc + (size_t)b * Ssz * Hh;
  int tid = threadIdx.x;
  int s = tid >> 2, q = tid & 3;
  const float* er = eb + (size_t)s * Hh + q * 256;
  const float* hq = hv + q * 256;
  float p = 0.f;
#pragma unroll 4
  for (int i = 0; i < 256; i += 4) {
    float4 a = *(const float4*)(hq + i);
    float4 c = *(const float4*)(er + i);
    p += a.x * c.x + a.y * c.y + a.z * c.z + a.w * c.w;
  }
  red[tid] = p;
  __syncthreads();
  if (tid < 64) {
    float sc = red[tid * 4] + red[tid * 4 + 1] + red[tid * 4 + 2] + red[tid * 4 + 3];
    float mx = sc;
#pragma unroll
    for (int off = 32; off > 0; off >>= 1) mx = fmaxf(mx, __shfl_xor(mx, off));
    float e = expf(sc - mx);
    float sm = e;
#pragma unroll
    for (int off = 32; off > 0; off >>= 1) sm += __shfl_xor(sm, off);
    wsm[tid] = e / sm;
  }
  __syncthreads();
  float* fr = feat + (size_t)m * FFc;
  for (int h = tid; h < Hh; h += 256) {
    float a = 0.f;
#pragma unroll 8
    for (int si = 0; si < Ssz; ++si) a = fmaf(wsm[si], eb[(size_t)si * Hh + h], a);
    fr[Hh + h] = a;
    fr[h] = hv[h];
  }
}

// training-mode BN over batch dim (per t). grid (CH/256, T)
__global__ void __launch_bounds__(256) bn_k(
    const float* __restrict__ x, const float* __restrict__ gam,
    const float* __restrict__ bet, bf16* __restrict__ y, int CH) {
  int t = blockIdx.y;
  int c = blockIdx.x * 256 + threadIdx.x;
  const float* xp = x + (size_t)t * Bb * CH + c;
  float v[Bb];
  float s = 0.f, ss = 0.f;
#pragma unroll
  for (int b = 0; b < Bb; ++b) {
    float u = xp[(size_t)b * CH];
    v[b] = u;
    s += u;
    ss += u * u;
  }
  float mean = s * (1.f / Bb);
  float var = ss * (1.f / Bb) - mean * mean;
  float inv = rsqrtf(var + 1e-5f);
  float sc = gam[c] * inv;
  float sh = bet[c] - mean * sc;
  bf16* yp = y + (size_t)t * Bb * CH + c;
#pragma unroll
  for (int b = 0; b < Bb; ++b) yp[(size_t)b * CH] = (bf16)(v[b] * sc + sh);
}

// softmax over V: bf16 logits (in the row's own f32 slot) -> f32 probs.
// Row held in registers (16 uint4/thread): one global read, one write.
__global__ void __launch_bounds__(256) softmax_k(float* __restrict__ out) {
  __shared__ float rm[256], rs[256];
  int m = blockIdx.x;
  int t = m >> 6, b = m & 63;
  size_t R = (size_t)b * Tt + t;
  const bf16* rin = (const bf16*)out + 2 * R * (size_t)Vv;
  float* rout = out + R * (size_t)Vv;
  int tid = threadIdx.x;
  uint4 v[16];
  float mx = -3.0e38f, sm = 0.f;
#pragma unroll
  for (int j = 0; j < 16; ++j) {
    int i = tid * 8 + j * 2048;
    if (i < Vv) {
      v[j] = *(const uint4*)(rin + i);
      const bf16* pv = (const bf16*)&v[j];
      float f0 = (float)pv[0], f1 = (float)pv[1], f2 = (float)pv[2], f3 = (float)pv[3];
      float f4 = (float)pv[4], f5 = (float)pv[5], f6 = (float)pv[6], f7 = (float)pv[7];
      float m8 = fmaxf(fmaxf(fmaxf(f0, f1), fmaxf(f2, f3)),
                       fmaxf(fmaxf(f4, f5), fmaxf(f6, f7)));
      if (m8 > mx) { sm *= expf(mx - m8); mx = m8; }
      sm += expf(f0 - mx) + expf(f1 - mx) + expf(f2 - mx) + expf(f3 - mx)
          + expf(f4 - mx) + expf(f5 - mx) + expf(f6 - mx) + expf(f7 - mx);
    }
  }
  rm[tid] = mx;
  rs[tid] = sm;
  __syncthreads();
  for (int off = 128; off > 0; off >>= 1) {
    if (tid < off) {
      float ma = rm[tid], mb = rm[tid + off];
      float m2 = fmaxf(ma, mb);
      rs[tid] = rs[tid] * expf(ma - m2) + rs[tid + off] * expf(mb - m2);
      rm[tid] = m2;
    }
    __syncthreads();
  }
  float M = rm[0];
  float inv = 1.f / rs[0];
#pragma unroll
  for (int j = 0; j < 16; ++j) {
    int i = tid * 8 + j * 2048;
    if (i < Vv) {
      const bf16* pv = (const bf16*)&v[j];
      float4 o0, o1;
      o0.x = expf((float)pv[0] - M) * inv;
      o0.y = expf((float)pv[1] - M) * inv;
      o0.z = expf((float)pv[2] - M) * inv;
      o0.w = expf((float)pv[3] - M) * inv;
      o1.x = expf((float)pv[4] - M) * inv;
      o1.y = expf((float)pv[5] - M) * inv;
      o1.z = expf((float)pv[6] - M) * inv;
      o1.w = expf((float)pv[7] - M) * inv;
      *(float4*)(rout + i) = o0;
      *(float4*)(rout + i + 4) = o1;
    }
  }
}

__global__ void hlast_k(const float* __restrict__ src, float* __restrict__ dst) {
  int i = blockIdx.x * 256 + threadIdx.x;
  dst[i] = src[i];
}

extern "C" void kernel_launch(void* const* d_in, const int* in_sizes, int n_in,
                              void* d_out, int out_size, void* d_ws, size_t ws_size,
                              hipStream_t stream) {
  const float* enc   = (const float*)d_in[0];
  const int*   label = (const int*)d_in[1];
  const float* h0    = (const float*)d_in[2];
  // d_in[3] answer_lens: unused by the forward pass
  const float* emb   = (const float*)d_in[4];
  const float* w_ih  = (const float*)d_in[5];
  const float* w_hh  = (const float*)d_in[6];
  const float* b_ih  = (const float*)d_in[7];
  const float* b_hh  = (const float*)d_in[8];
  const float* bn1g  = (const float*)d_in[9];
  const float* bn1b  = (const float*)d_in[10];
  const float* W1    = (const float*)d_in[11];
  const float* b1    = (const float*)d_in[12];
  const float* bn2g  = (const float*)d_in[13];
  const float* bn2b  = (const float*)d_in[14];
  const float* W2    = (const float*)d_in[15];
  const float* b2    = (const float*)d_in[16];
  float* out = (float*)d_out;
  (void)in_sizes; (void)n_in; (void)out_size; (void)ws_size;

  char* ws = (char*)d_ws;
  size_t off = 0;
  auto alloc = [&](size_t bytes) -> void* {
    void* p = ws + off;
    off += (bytes + 255) & ~(size_t)255;
    return p;
  };
  // workspace layout IDENTICAL to round-13 green run
  bf16*  W2t   = (bf16*)alloc((size_t)Vv * Hh * 2);        // 64 MB
  bf16*  W1t   = (bf16*)alloc((size_t)Hh * FFc * 2);       // 4 MB
  bf16*  wihB  = (bf16*)alloc((size_t)G3c * Ee * 2);       // 3 MB
  bf16*  whhHi = (bf16*)alloc((size_t)G3c * Hh * 2);       // 6 MB
  bf16*  whhLo = (bf16*)alloc((size_t)G3c * Hh * 2);       // 6 MB
  bf16*  xeB   = (bf16*)alloc((size_t)TBm * Ee * 2);       // 2 MB
  float* gates = (float*)alloc((size_t)TBm * G3c * 4);     // 25 MB
  float* hseq  = (float*)alloc((size_t)Tt * Bb * Hh * 4);  // 8 MB
  bf16*  hHi0  = (bf16*)alloc((size_t)Bb * Hh * 2);
  bf16*  hHi1  = (bf16*)alloc((size_t)Bb * Hh * 2);
  bf16*  hLo0  = (bf16*)alloc((size_t)Bb * Hh * 2);
  bf16*  hLo1  = (bf16*)alloc((size_t)Bb * Hh * 2);
  u32*   bar   = (u32*)alloc(2048);                        // 8 counter lines
  float* feat  = gates;  // alias: gates dead after GRU; 16 MB <= 25 MB
  bf16*  featB = (bf16*)alloc((size_t)TBm * FFc * 2);      // 8 MB
  float* Y     = (float*)alloc((size_t)TBm * Hh * 4);      // 8 MB
  bf16*  ybB   = (bf16*)alloc((size_t)TBm * Hh * 2);       // 4 MB

  // ---- zero barrier counters (re-zeroed every launch; graph-safe) ----
  zero_k<<<1, 512, 0, stream>>>(bar, 512);

  // ---- weight prep ----
  cvt_simple_k<<<1024, 256, 0, stream>>>(w_ih, wihB, G3c * Ee);
  cvt_split_k<<<2048, 256, 0, stream>>>(w_hh, whhHi, whhLo, G3c * Hh);
  transpose_cvt_k<<<dim3(Hh / 32, FFc / 32), 256, 0, stream>>>(W1, W1t, FFc, Hh);
  transpose_cvt_k<<<dim3(Vv / 32, Hh / 32), 256, 0, stream>>>(W2, W2t, Hh, Vv);
  embed_k<<<TBm, 128, 0, stream>>>(emb, label, xeB);
  cvt_split_k<<<256, 256, 0, stream>>>(h0, hHi0, hLo0, Bb * Hh);

  // ---- gates_x = x_emb @ w_ih^T + b_ih  [TB, 3H] ----
  gemm_nt_k<0><<<dim3(G3c / 128, TBm / 128), 256, 0, stream>>>(
      xeB, wihB, b_ih, gates, TBm, G3c, Ee);

  // ---- fused sequential GRU (persistent, 8-line atomic barrier) ----
  gru_all_k<<<NBLKG, 256, 0, stream>>>(
      hHi0, hLo0, hHi1, hLo1, whhHi, whhLo, gates, b_hh, h0, hseq, bar);

  // ---- batched post-recurrence pipeline ----
  attn_k<<<TBm, 256, 0, stream>>>(hseq, enc, feat);
  bn_k<<<dim3(FFc / 256, Tt), 256, 0, stream>>>(feat, bn1g, bn1b, featB, FFc);
  gemm_nt_k<1><<<dim3(Hh / 128, TBm / 128), 256, 0, stream>>>(
      featB, W1t, b1, Y, TBm, Hh, FFc);
  bn_k<<<dim3(Hh / 256, Tt), 256, 0, stream>>>(Y, bn2g, bn2b, ybB, Hh);
  gemm_nt_k<2><<<dim3(Vv / 128, TBm / 128), 256, 0, stream>>>(
      ybB, W2t, b2, out, TBm, Vv, Hh);
  softmax_k<<<TBm, 256, 0, stream>>>(out);
  hlast_k<<<(Bb * Hh) / 256, 256, 0, stream>>>(
      hseq + (size_t)(Tt - 1) * Bb * Hh, out + (size_t)Bb * Tt * Vv);
}